// Round 1
// baseline (642.986 us; speedup 1.0000x reference)
//
#include <hip/hip_runtime.h>
#include <hip/hip_bf16.h>

// scores[u,i] = -(||U[u]||^2 + ||I[i]||^2 - 2 U[u].I[i])
// M=256 users (gathered), N=500000 items, K=64. fp32 in/out.
// Strategy: bf16 MFMA for the cross term (16.4 GF -> free), fp32 norms,
// memory-bound on the 512 MB output write.

#define DIM 64
#define NSCORE 256

typedef short bf16x8 __attribute__((ext_vector_type(8)));
typedef float f32x4 __attribute__((ext_vector_type(4)));

__device__ __forceinline__ short f2bf(float f) {
    union { float f; unsigned u; } v; v.f = f;
    unsigned r = v.u + 0x7FFF + ((v.u >> 16) & 1);   // RTN-even
    return (short)(r >> 16);
}

// Prep: gather 256 users, u_sq (fp32), write A bf16 in MFMA-fragment order:
// ws_A elem offset = (ut*2+ks)*512 + lane*8 + j,  lane = quad*16 + (u&15),
// where for element k of user u: ks=k>>5, quad=(k&31)>>3, j=k&7, ut=u>>4.
// grid 16 x block 256: thread t -> user t>>4, seg t&15 (4 floats).
__global__ void prep_users(const int* __restrict__ uid,
                           const float* __restrict__ U,
                           short* __restrict__ wsA,
                           float* __restrict__ ws_usq) {
    int t = blockIdx.x * blockDim.x + threadIdx.x;   // 0..4095
    int u   = t >> 4;
    int seg = t & 15;
    int id = uid[u];
    float4 x = *(const float4*)(U + (long)id * DIM + seg * 4);
    float s = x.x * x.x + x.y * x.y + x.z * x.z + x.w * x.w;
    #pragma unroll
    for (int off = 1; off < 16; off <<= 1) s += __shfl_xor(s, off, 16);
    if (seg == 0) ws_usq[u] = s;

    int ks   = seg >> 3;          // (seg*4)>>5
    int quad = (seg & 7) >> 1;    // ((seg*4)&31)>>3
    int j0   = (seg & 1) * 4;     // (seg*4)&7
    int ut   = u >> 4;
    int lane = quad * 16 + (u & 15);
    short4 b;
    b.x = f2bf(x.x); b.y = f2bf(x.y); b.z = f2bf(x.z); b.w = f2bf(x.w);
    *(short4*)(wsA + (ut * 2 + ks) * 512 + lane * 8 + j0) = b;
}

// Main: block = 256 threads = 4 waves. Block tile: 256 users x 64 items.
// Wave w: items [i0+16w, i0+16w+16), all 16 user-tiles -> 32 MFMAs/wave.
#define BROW 72   // padded LDS row (bf16) for the item tile

__global__ __launch_bounds__(256)
void cml_main(const float* __restrict__ I,
              const short* __restrict__ wsA,
              const float* __restrict__ ws_usq,
              float* __restrict__ out,
              int n_items) {
    __shared__ __align__(16) short sB[64 * BROW];
    __shared__ float sIsq[64];
    __shared__ float sUsq[NSCORE];

    int t  = threadIdx.x;
    int i0 = blockIdx.x * 64;

    sUsq[t] = ws_usq[t];

    // Stage item tile: 64 rows x 64 dims fp32 -> bf16 LDS + i_sq.
    // f = c*256 + t; row = f>>4, seg = f&15 (4 floats).
    #pragma unroll
    for (int c = 0; c < 4; c++) {
        int f   = c * 256 + t;
        int row = f >> 4;
        int seg = f & 15;
        int gi  = i0 + row;
        float4 x = make_float4(0.f, 0.f, 0.f, 0.f);
        if (gi < n_items)
            x = *(const float4*)(I + (long)gi * DIM + seg * 4);
        float s = x.x * x.x + x.y * x.y + x.z * x.z + x.w * x.w;
        #pragma unroll
        for (int off = 1; off < 16; off <<= 1) s += __shfl_xor(s, off, 16);
        short4 b;
        b.x = f2bf(x.x); b.y = f2bf(x.y); b.z = f2bf(x.z); b.w = f2bf(x.w);
        *(short4*)(sB + row * BROW + seg * 4) = b;
        if (seg == 0) sIsq[row] = s;
    }
    __syncthreads();

    int w    = t >> 6;
    int l    = t & 63;
    int m16  = l & 15;
    int quad = l >> 4;

    // B frags: item row (16w + m16), k-chunk quad*8 (+32 for ks=1)
    const short* bp = sB + (16 * w + m16) * BROW + quad * 8;
    bf16x8 bfr0 = *(const bf16x8*)(bp);
    bf16x8 bfr1 = *(const bf16x8*)(bp + 32);

    f32x4 acc[16];
    #pragma unroll
    for (int ut = 0; ut < 16; ut++) acc[ut] = (f32x4){0.f, 0.f, 0.f, 0.f};

    const bf16x8* Afrag = (const bf16x8*)wsA;   // [(ut*2+ks)*64 + lane]
    #pragma unroll
    for (int ut = 0; ut < 16; ut++) {
        bf16x8 a0 = Afrag[(ut * 2 + 0) * 64 + l];
        bf16x8 a1 = Afrag[(ut * 2 + 1) * 64 + l];
        acc[ut] = __builtin_amdgcn_mfma_f32_16x16x32_bf16(a0, bfr0, acc[ut], 0, 0, 0);
        acc[ut] = __builtin_amdgcn_mfma_f32_16x16x32_bf16(a1, bfr1, acc[ut], 0, 0, 0);
    }

    // Epilogue: C/D layout col=lane&15, row=quad*4+r.
    int nloc = 16 * w + m16;
    int gi   = i0 + nloc;
    if (gi < n_items) {
        float isq = sIsq[nloc];
        #pragma unroll
        for (int ut = 0; ut < 16; ut++) {
            int u0 = ut * 16 + quad * 4;
            #pragma unroll
            for (int r = 0; r < 4; r++) {
                int u = u0 + r;
                out[(size_t)u * n_items + gi] = 2.0f * acc[ut][r] - sUsq[u] - isq;
            }
        }
    }
}

extern "C" void kernel_launch(void* const* d_in, const int* in_sizes, int n_in,
                              void* d_out, int out_size, void* d_ws, size_t ws_size,
                              hipStream_t stream) {
    const int*   uid = (const int*)d_in[0];
    const float* U   = (const float*)d_in[1];
    const float* I   = (const float*)d_in[2];
    float*       out = (float*)d_out;
    int n_items = in_sizes[2] / DIM;

    short* wsA    = (short*)d_ws;
    float* ws_usq = (float*)((char*)d_ws + (size_t)NSCORE * DIM * sizeof(short));

    prep_users<<<16, 256, 0, stream>>>(uid, U, wsA, ws_usq);
    int nblocks = (n_items + 63) / 64;
    cml_main<<<nblocks, 256, 0, stream>>>(I, wsA, ws_usq, out, n_items);
}